// Round 2
// baseline (106.426 us; speedup 1.0000x reference)
//
#include <hip/hip_runtime.h>
#include <hip/hip_bf16.h>

#define EPSF 1e-7f
#define B_ 8
#define H_ 64
#define W_ 64
#define C_ 32
#define HO 58
#define WO 58
#define NF 64
#define KDIM 800

#define XBS 40      // xtb channel stride (bf16): 80B -> +20 banks/col, 16B-aligned

typedef __bf16 v8bf __attribute__((ext_vector_type(8)));
typedef float  v4f  __attribute__((ext_vector_type(4)));
typedef float  v2f  __attribute__((ext_vector_type(2)));

// ---- fused: block = 4 output rows x 16 cols; wave = 1 row x 16 px x 64 f.
// A-fragments built in registers; W B-fragments loaded inline from raw fp32 W
// (no workspace => no 256MB ws re-poison in the timed region).
__global__ __launch_bounds__(256, 2)
void k_main(const float* __restrict__ x, const float* __restrict__ W,
            const float* __restrict__ bias, float* __restrict__ out) {
    __shared__ __bf16 xtb[10][22][XBS];   // 17,600 B
    __shared__ float  Srow[10][22];       //    880 B
    __shared__ float4 pars[64];           //  1,024 B  -> 19,504 B total

    int tid = threadIdx.x;
    int wv = tid >> 6, lane = tid & 63;
    int m = lane & 15, q = lane >> 4;

    // XCD-aware remap over 480 blocks: b == XCD id (x slice + W stay in L2)
    int L = blockIdx.x + 4*(blockIdx.y + 15*blockIdx.z);   // 0..479
    int newL = (L & 7)*60 + (L >> 3);
    int b   = newL / 60;
    int rem = newL - b*60;                 // 0..59
    int rg  = rem >> 2;                    // 0..14 -> row group of 4
    int cg  = rem & 3;                     // 0..3  -> col group of 16
    int ho0 = rg*4, wo0 = cg*16;
    int npx = WO - wo0; if (npx > 16) npx = 16;   // 16,16,16,10

    // phase 0: stage 10 rows x 22 cols x 32ch; fp32 sums -> Srow, bf16 -> xtb.
    // Edge rows/cols clamped (dup of last row/col); dups only feed masked px.
    if (tid < 220) {
        int r = tid / 22, c = tid - r*22;
        int xr = ho0 + r; if (xr > H_-1) xr = H_-1;
        int xc = wo0 + c; if (xc > W_-1) xc = W_-1;
        const float* src = x + (size_t)((b*H_ + xr)*W_ + xc)*C_;
        float4 vq[8];
#pragma unroll
        for (int qq = 0; qq < 8; qq++) vq[qq] = *(const float4*)(src + qq*4);
        float s = 0.f;
#pragma unroll
        for (int qq = 0; qq < 8; qq++) s += vq[qq].x + vq[qq].y + vq[qq].z + vq[qq].w;
        Srow[r][c] = s;
#pragma unroll
        for (int h8 = 0; h8 < 4; h8++) {
            v8bf o;
            o[0]=(__bf16)vq[h8*2].x;   o[1]=(__bf16)vq[h8*2].y;
            o[2]=(__bf16)vq[h8*2].z;   o[3]=(__bf16)vq[h8*2].w;
            o[4]=(__bf16)vq[h8*2+1].x; o[5]=(__bf16)vq[h8*2+1].y;
            o[6]=(__bf16)vq[h8*2+1].z; o[7]=(__bf16)vq[h8*2+1].w;
            *(v8bf*)&xtb[r][c][h8*8] = o;
        }
    }
    __syncthreads();

    // phase 1: per-pixel rotation params, 1 thread per px (64 px/block)
    if (tid < 64) {
        int r0 = tid >> 4, c0 = tid & 15;
        float den = 0.f, crn = 0.f, ccn = 0.f;
#pragma unroll
        for (int i = 0; i < 7; i++)
#pragma unroll
            for (int j = 0; j < 7; j++) {
                float v = Srow[r0 + i][c0 + j];
                den += v; crn += v*(float)i; ccn += v*(float)j;
            }
        float dt = den + EPSF;
        float cr = crn/dt - 3.0f;
        float cx = ccn/dt - 3.0f + EPSF;
        float r2 = cr*cr + cx*cx;
        float inv = r2 > 0.f ? rsqrtf(r2) : 0.f;
        float c_ = r2 > 0.f ? cx*inv : 1.0f;
        float s_ = cr*inv;
        const float scale = 1.0f + EPSF;
        float pc  = c_/scale, ps = s_/scale;
        float pxo = (6.0f - (c_*6.0f - s_*6.0f))*0.5f/scale;
        float pyo = (6.0f - (s_*6.0f + c_*6.0f))*0.5f/scale;
        pars[tid] = make_float4(pc, ps, pxo, pyo);
    }
    __syncthreads();
    // ---- no more barriers: xtb/pars are read-only from here ----

    float4 pp = pars[(wv << 4) | m];       // params of this lane's pixel
    float pc = pp.x, ps = pp.y, pxo = pp.z, pyo = pp.w;

    float bv[4];
#pragma unroll
    for (int nt = 0; nt < 4; nt++) bv[nt] = bias[nt*16 + m];

    // B-fragment source: lane reads W[f=nt*16+m][kb*32 + q*8 .. +7] (8 floats)
    const float* wrow = W + (size_t)m*KDIM + q*8;
    const __bf16* patch = &xtb[wv][m][q*8];   // 7x7 window base, ch-slice q

    v4f acc0 = {0.f,0.f,0.f,0.f}, acc1 = {0.f,0.f,0.f,0.f};
    v4f acc2 = {0.f,0.f,0.f,0.f}, acc3 = {0.f,0.f,0.f,0.f};

#pragma unroll 1
    for (int py = 0; py < 5; py++) {
        float yy = (float)(py + 1);
#pragma unroll
        for (int pxx = 0; pxx < 5; pxx++) {
            int kb = py*5 + pxx;
            float xx = (float)(pxx + 1);

            // inline W fragments: 2x float4 + cvt (same RTNE as old k_wpack)
            v8bf wf[4];
#pragma unroll
            for (int nt = 0; nt < 4; nt++) {
                const float* wsrc = wrow + nt*16*KDIM + kb*32;
                float4 lo = *(const float4*)(wsrc);
                float4 hi = *(const float4*)(wsrc + 4);
                v8bf o;
                o[0]=(__bf16)lo.x; o[1]=(__bf16)lo.y;
                o[2]=(__bf16)lo.z; o[3]=(__bf16)lo.w;
                o[4]=(__bf16)hi.x; o[5]=(__bf16)hi.y;
                o[6]=(__bf16)hi.z; o[7]=(__bf16)hi.w;
                wf[nt] = o;
            }

            float xin = pc*xx - ps*yy + pxo;
            float yin = ps*xx + pc*yy + pyo;
            float x0f = floorf(xin), y0f = floorf(yin);
            float wx1 = xin - x0f, wx0 = 1.0f - wx1;
            float wy1 = yin - y0f, wy0 = 1.0f - wy1;
            int ix0 = (int)x0f, iy0 = (int)y0f;
            int ix1 = ix0 + 1,  iy1 = iy0 + 1;

            v2f a8[4];
#pragma unroll
            for (int d = 0; d < 4; d++) a8[d] = (v2f){0.f, 0.f};

            auto corner = [&](int yi, int xi, float wgt) {
                bool valid = (xi >= 0) & (xi < 7) & (yi >= 0) & (yi < 7);
                int cy  = yi < 0 ? 0 : (yi > 6 ? 6 : yi);
                int cx2 = xi < 0 ? 0 : (xi > 6 ? 6 : xi);
                float wq = valid ? wgt : 0.0f;
                union { v8bf v; unsigned u[4]; } uv;
                uv.v = *(const v8bf*)(patch + (cy*22 + cx2)*XBS);
                v2f w2 = (v2f){wq, wq};
#pragma unroll
                for (int d = 0; d < 4; d++) {
                    v2f val = (v2f){ __uint_as_float(uv.u[d] << 16),
                                     __uint_as_float(uv.u[d] & 0xffff0000u) };
                    a8[d] += w2 * val;   // v_pk_fma_f32
                }
            };
            corner(iy0, ix0, wy0*wx0);
            corner(iy0, ix1, wy0*wx1);
            corner(iy1, ix0, wy1*wx0);
            corner(iy1, ix1, wy1*wx1);

            v8bf af;   // A-fragment: row=m(px col), k=kb*32+q*8..+8
#pragma unroll
            for (int d = 0; d < 4; d++) {
                af[2*d]   = (__bf16)a8[d].x;
                af[2*d+1] = (__bf16)a8[d].y;
            }
            acc0 = __builtin_amdgcn_mfma_f32_16x16x32_bf16(af, wf[0], acc0, 0, 0, 0);
            acc1 = __builtin_amdgcn_mfma_f32_16x16x32_bf16(af, wf[1], acc1, 0, 0, 0);
            acc2 = __builtin_amdgcn_mfma_f32_16x16x32_bf16(af, wf[2], acc2, 0, 0, 0);
            acc3 = __builtin_amdgcn_mfma_f32_16x16x32_bf16(af, wf[3], acc3, 0, 0, 0);
        }
    }

    // epilogue: D col=lane&15 -> f_lo=m, D row=q*4+r -> pixel col
    int ho = ho0 + wv;
    if (ho < HO) {
        size_t rowbase = (size_t)(b*HO + ho)*WO + wo0;
#pragma unroll
        for (int r = 0; r < 4; r++) {
            int px = q*4 + r;
            if (px < npx) {
                float* op = out + (rowbase + px)*NF + m;
                op[0]  = acc0[r] + bv[0];
                op[16] = acc1[r] + bv[1];
                op[32] = acc2[r] + bv[2];
                op[48] = acc3[r] + bv[3];
            }
        }
    }
}

extern "C" void kernel_launch(void* const* d_in, const int* in_sizes, int n_in,
                              void* d_out, int out_size, void* d_ws, size_t ws_size,
                              hipStream_t stream) {
    const float* x    = (const float*)d_in[0];
    const float* W    = (const float*)d_in[1];
    const float* bias = (const float*)d_in[2];
    float* out = (float*)d_out;
    (void)d_ws; (void)ws_size;   // workspace intentionally unused

    k_main<<<dim3(4, 15, 8), 256, 0, stream>>>(x, W, bias, out);
}

// Round 3
// 76.831 us; speedup vs baseline: 1.3852x; 1.3852x over previous
//
#include <hip/hip_runtime.h>
#include <hip/hip_bf16.h>

#define EPSF 1e-7f
#define B_ 8
#define H_ 64
#define W_ 64
#define C_ 32
#define HO 58
#define WO 58
#define NF 64
#define KDIM 800

#define XBS 40      // xtb channel stride (bf16): 80B -> +20 banks/col, balanced 8/bank

typedef __bf16 v8bf __attribute__((ext_vector_type(8)));
typedef float  v4f  __attribute__((ext_vector_type(4)));
typedef float  v2f  __attribute__((ext_vector_type(2)));

// ---- pack W into MFMA B-fragment order, bf16 (proven) ----
// Wp[((nt*25+kb)*64+lane)*8+j] = W[f=nt*16+(lane&15)][k=kb*32+(lane>>4)*8+j]
__global__ void k_wpack(const float* __restrict__ W, __bf16* __restrict__ Wp) {
    int t = blockIdx.x*256 + threadIdx.x;   // 51200 total
    int j = t & 7; int lane = (t >> 3) & 63; int rest = t >> 9;
    int kb = rest % 25; int nt = rest / 25;
    int f = nt*16 + (lane & 15);
    int k = kb*32 + (lane >> 4)*8 + j;
    Wp[t] = (__bf16)W[f*KDIM + k];
}

// ---- fused: block = 2 rows x 16 cols, 4 waves = (row rh, K-half kh).
// Split-K doubles wave count (3712 waves ~ 3.6/SIMD); W double-buffered.
__global__ __launch_bounds__(256, 4)
void k_main(const float* __restrict__ x, const v8bf* __restrict__ Wp,
            const float* __restrict__ bias, float* __restrict__ out) {
    __shared__ __bf16 xtb[8][22][XBS];    // 14,080 B
    __shared__ float  Srow[8][22];        //    704 B
    __shared__ float4 pars[32];           //    512 B
    __shared__ float  redu[2][64][20];    // 10,240 B -> 25,536 B total

    int tid = threadIdx.x;
    int wv = tid >> 6, lane = tid & 63;
    int m = lane & 15, q = lane >> 4;
    int rh = wv & 1, kh = wv >> 1;

    // XCD-aware remap over 928 blocks (8 x 116, bijective)
    int L = blockIdx.x + 4*(blockIdx.y + 29*blockIdx.z);   // 0..927
    int newL = (L & 7)*116 + (L >> 3);
    int b   = newL / 116;
    int rem = newL - b*116;                // 0..115
    int rg  = rem >> 2;                    // 0..28 -> row group of 2
    int cg  = rem & 3;                     // 0..3  -> col group of 16
    int ho0 = rg*2, wo0 = cg*16;
    int npx = WO - wo0; if (npx > 16) npx = 16;   // 16,16,16,10

    // phase 0: stage 8 rows x 22 cols x 32ch (rows never clamp: ho0+7 <= 63)
    if (tid < 176) {
        int r = tid / 22, c = tid - r*22;
        int xc = wo0 + c; if (xc > W_-1) xc = W_-1;
        const float* src = x + (size_t)((b*H_ + ho0 + r)*W_ + xc)*C_;
        float4 vq[8];
#pragma unroll
        for (int qq = 0; qq < 8; qq++) vq[qq] = *(const float4*)(src + qq*4);
        float s = 0.f;
#pragma unroll
        for (int qq = 0; qq < 8; qq++) s += vq[qq].x + vq[qq].y + vq[qq].z + vq[qq].w;
        Srow[r][c] = s;
#pragma unroll
        for (int h8 = 0; h8 < 4; h8++) {
            v8bf o;
            o[0]=(__bf16)vq[h8*2].x;   o[1]=(__bf16)vq[h8*2].y;
            o[2]=(__bf16)vq[h8*2].z;   o[3]=(__bf16)vq[h8*2].w;
            o[4]=(__bf16)vq[h8*2+1].x; o[5]=(__bf16)vq[h8*2+1].y;
            o[6]=(__bf16)vq[h8*2+1].z; o[7]=(__bf16)vq[h8*2+1].w;
            *(v8bf*)&xtb[r][c][h8*8] = o;
        }
    }
    __syncthreads();

    // phase 1: per-pixel rotation params, 1 thread per px (32 px/block)
    if (tid < 32) {
        int r0 = tid >> 4, c0 = tid & 15;
        float den = 0.f, crn = 0.f, ccn = 0.f;
#pragma unroll
        for (int i = 0; i < 7; i++)
#pragma unroll
            for (int j = 0; j < 7; j++) {
                float v = Srow[r0 + i][c0 + j];
                den += v; crn += v*(float)i; ccn += v*(float)j;
            }
        float dt = den + EPSF;
        float cr = crn/dt - 3.0f;
        float cx = ccn/dt - 3.0f + EPSF;
        float r2 = cr*cr + cx*cx;
        float inv = r2 > 0.f ? rsqrtf(r2) : 0.f;
        float c_ = r2 > 0.f ? cx*inv : 1.0f;
        float s_ = cr*inv;
        const float scale = 1.0f + EPSF;
        float pc  = c_/scale, ps = s_/scale;
        float pxo = (6.0f - (c_*6.0f - s_*6.0f))*0.5f/scale;
        float pyo = (6.0f - (s_*6.0f + c_*6.0f))*0.5f/scale;
        pars[tid] = make_float4(pc, ps, pxo, pyo);
    }
    __syncthreads();
    // ---- xtb/pars read-only until the reduction barrier ----

    float4 pp = pars[(rh << 4) | m];       // params of this lane's pixel
    float pc = pp.x, ps = pp.y, pxo = pp.z, pyo = pp.w;

    const v8bf* wp = Wp + lane;            // + (nt*25+kb)*64
    const __bf16* patch = &xtb[rh][m][q*8];   // 7x7 window base, ch-slice q

    v4f acc0 = {0.f,0.f,0.f,0.f}, acc1 = {0.f,0.f,0.f,0.f};
    v4f acc2 = {0.f,0.f,0.f,0.f}, acc3 = {0.f,0.f,0.f,0.f};

    int kb0 = kh*13;                       // kh=0: kb 0..12; kh=1: kb 13..24
    int nkb = 13 - kh;
    int kblast = kb0 + nkb - 1;

    auto loadw = [&](v8bf* dst, int kbi) {
        dst[0] = wp[(0*25 + kbi)*64];
        dst[1] = wp[(1*25 + kbi)*64];
        dst[2] = wp[(2*25 + kbi)*64];
        dst[3] = wp[(3*25 + kbi)*64];
    };

    auto body = [&](int kb, const v8bf* wf) {
        unsigned ukb = (unsigned)kb;
        int py = (int)(ukb/5u);
        int pxx = kb - py*5;
        float yy = (float)(py + 1);
        float xx = (float)(pxx + 1);

        float xin = pc*xx - ps*yy + pxo;
        float yin = ps*xx + pc*yy + pyo;
        float x0f = floorf(xin), y0f = floorf(yin);
        float wx1 = xin - x0f, wx0 = 1.0f - wx1;
        float wy1 = yin - y0f, wy0 = 1.0f - wy1;
        int ix0 = (int)x0f, iy0 = (int)y0f;
        int ix1 = ix0 + 1,  iy1 = iy0 + 1;

        v2f a8[4];
#pragma unroll
        for (int d = 0; d < 4; d++) a8[d] = (v2f){0.f, 0.f};

        auto corner = [&](int yi, int xi, float wgt) {
            bool valid = (xi >= 0) & (xi < 7) & (yi >= 0) & (yi < 7);
            int cy  = yi < 0 ? 0 : (yi > 6 ? 6 : yi);
            int cx2 = xi < 0 ? 0 : (xi > 6 ? 6 : xi);
            float wq = valid ? wgt : 0.0f;
            union { v8bf v; unsigned u[4]; } uv;
            uv.v = *(const v8bf*)(patch + (cy*22 + cx2)*XBS);
            v2f w2 = (v2f){wq, wq};
#pragma unroll
            for (int d = 0; d < 4; d++) {
                v2f val = (v2f){ __uint_as_float(uv.u[d] << 16),
                                 __uint_as_float(uv.u[d] & 0xffff0000u) };
                a8[d] += w2 * val;   // v_pk_fma_f32
            }
        };
        corner(iy0, ix0, wy0*wx0);
        corner(iy0, ix1, wy0*wx1);
        corner(iy1, ix0, wy1*wx0);
        corner(iy1, ix1, wy1*wx1);

        v8bf af;   // A-fragment: row=m(px col), k=kb*32+q*8..+8
#pragma unroll
        for (int d = 0; d < 4; d++) {
            af[2*d]   = (__bf16)a8[d].x;
            af[2*d+1] = (__bf16)a8[d].y;
        }
        acc0 = __builtin_amdgcn_mfma_f32_16x16x32_bf16(af, wf[0], acc0, 0, 0, 0);
        acc1 = __builtin_amdgcn_mfma_f32_16x16x32_bf16(af, wf[1], acc1, 0, 0, 0);
        acc2 = __builtin_amdgcn_mfma_f32_16x16x32_bf16(af, wf[2], acc2, 0, 0, 0);
        acc3 = __builtin_amdgcn_mfma_f32_16x16x32_bf16(af, wf[3], acc3, 0, 0, 0);
    };

    // ping-pong W double-buffer: loads for step k+1 in flight during step k
    v8bf wfA[4], wfB[4];
    loadw(wfA, kb0);
    int i = 0;
#pragma unroll 1
    for (; i + 2 <= nkb; i += 2) {
        loadw(wfB, kb0 + i + 1);
        body(kb0 + i, wfA);
        int nx = kb0 + i + 2; if (nx > kblast) nx = kblast;
        loadw(wfA, nx);
        body(kb0 + i + 1, wfB);
    }
    if (i < nkb) body(kblast, wfA);        // tail (kh=0 only: 13th step)

    // split-K reduction: kh=1 waves publish, kh=0 waves sum + store
    if (kh == 1) {
        *(v4f*)&redu[rh][lane][0]  = acc0;
        *(v4f*)&redu[rh][lane][4]  = acc1;
        *(v4f*)&redu[rh][lane][8]  = acc2;
        *(v4f*)&redu[rh][lane][12] = acc3;
    }
    __syncthreads();
    if (kh == 0) {
        acc0 += *(const v4f*)&redu[rh][lane][0];
        acc1 += *(const v4f*)&redu[rh][lane][4];
        acc2 += *(const v4f*)&redu[rh][lane][8];
        acc3 += *(const v4f*)&redu[rh][lane][12];

        float bv0 = bias[m], bv1 = bias[16 + m];
        float bv2 = bias[32 + m], bv3 = bias[48 + m];

        int ho = ho0 + rh;                 // always < 58
        size_t rowbase = (size_t)(b*HO + ho)*WO + wo0;
#pragma unroll
        for (int r = 0; r < 4; r++) {
            int px = q*4 + r;              // D row = (lane>>4)*4 + reg -> pixel col
            if (px < npx) {
                float* op = out + (rowbase + px)*NF + m;
                op[0]  = acc0[r] + bv0;
                op[16] = acc1[r] + bv1;
                op[32] = acc2[r] + bv2;
                op[48] = acc3[r] + bv3;
            }
        }
    }
}

extern "C" void kernel_launch(void* const* d_in, const int* in_sizes, int n_in,
                              void* d_out, int out_size, void* d_ws, size_t ws_size,
                              hipStream_t stream) {
    const float* x    = (const float*)d_in[0];
    const float* W    = (const float*)d_in[1];
    const float* bias = (const float*)d_in[2];
    float* out = (float*)d_out;
    __bf16* Wp = (__bf16*)d_ws;                    // 102,400 B

    k_wpack<<<dim3(200), 256, 0, stream>>>(W, Wp);
    k_main<<<dim3(4, 29, B_), 256, 0, stream>>>(x, (const v8bf*)Wp, bias, out);
}

// Round 5
// 76.534 us; speedup vs baseline: 1.3906x; 1.0039x over previous
//
#include <hip/hip_runtime.h>
#include <hip/hip_bf16.h>

#define EPSF 1e-7f
#define B_ 8
#define H_ 64
#define W_ 64
#define C_ 32
#define HO 58
#define WO 58
#define NF 64
#define KDIM 800

#define XBS 40      // xtb channel stride (bf16): 80B -> +20 banks/col, balanced 8/bank

typedef __bf16 v8bf __attribute__((ext_vector_type(8)));
typedef float  v4f  __attribute__((ext_vector_type(4)));
typedef float  v2f  __attribute__((ext_vector_type(2)));

// ---- pack W into MFMA B-fragment order, bf16 (proven) ----
// Wp[((nt*25+kb)*64+lane)*8+j] = W[f=nt*16+(lane&15)][k=kb*32+(lane>>4)*8+j]
__global__ void k_wpack(const float* __restrict__ W, __bf16* __restrict__ Wp) {
    int t = blockIdx.x*256 + threadIdx.x;   // 51200 total
    int j = t & 7; int lane = (t >> 3) & 63; int rest = t >> 9;
    int kb = rest % 25; int nt = rest / 25;
    int f = nt*16 + (lane & 15);
    int k = kb*32 + (lane >> 4)*8 + j;
    Wp[t] = (__bf16)W[f*KDIM + k];
}

// ---- fused: block = 2 rows x 16 cols, 8 waves = (row rh, K-quarter kh).
// Split-K x4: 7424 waves ~ 7.25/SIMD (2x round-3 TLP). Proven loop body.
__global__ __launch_bounds__(512, 8)
void k_main(const float* __restrict__ x, const v8bf* __restrict__ Wp,
            const float* __restrict__ bias, float* __restrict__ out) {
    __shared__ __bf16 xtb[8][22][XBS];    // 14,080 B
    __shared__ float  Srow[8][22];        //    704 B
    __shared__ float4 pars[32];           //    512 B
    __shared__ float  redu[3][2][64][16]; // 24,576 B -> 39,872 B total (4/CU)

    int tid = threadIdx.x;
    int wv = tid >> 6, lane = tid & 63;
    int m = lane & 15, q = lane >> 4;
    int rh = wv & 1, kh = wv >> 1;        // kh in 0..3

    // XCD-aware remap over 928 blocks (8 x 116, bijective)
    int L = blockIdx.x + 4*(blockIdx.y + 29*blockIdx.z);   // 0..927
    int newL = (L & 7)*116 + (L >> 3);
    int b   = newL / 116;
    int rem = newL - b*116;                // 0..115
    int rg  = rem >> 2;                    // 0..28 -> row group of 2
    int cg  = rem & 3;                     // 0..3  -> col group of 16
    int ho0 = rg*2, wo0 = cg*16;
    int npx = WO - wo0; if (npx > 16) npx = 16;   // 16,16,16,10

    // phase 0: stage 8 rows x 22 cols x 32ch (rows never clamp: ho0+7 <= 63)
    if (tid < 176) {
        int r = tid / 22, c = tid - r*22;
        int xc = wo0 + c; if (xc > W_-1) xc = W_-1;
        const float* src = x + (size_t)((b*H_ + ho0 + r)*W_ + xc)*C_;
        float4 vq[8];
#pragma unroll
        for (int qq = 0; qq < 8; qq++) vq[qq] = *(const float4*)(src + qq*4);
        float s = 0.f;
#pragma unroll
        for (int qq = 0; qq < 8; qq++) s += vq[qq].x + vq[qq].y + vq[qq].z + vq[qq].w;
        Srow[r][c] = s;
#pragma unroll
        for (int h8 = 0; h8 < 4; h8++) {
            v8bf o;
            o[0]=(__bf16)vq[h8*2].x;   o[1]=(__bf16)vq[h8*2].y;
            o[2]=(__bf16)vq[h8*2].z;   o[3]=(__bf16)vq[h8*2].w;
            o[4]=(__bf16)vq[h8*2+1].x; o[5]=(__bf16)vq[h8*2+1].y;
            o[6]=(__bf16)vq[h8*2+1].z; o[7]=(__bf16)vq[h8*2+1].w;
            *(v8bf*)&xtb[r][c][h8*8] = o;
        }
    }
    __syncthreads();

    // phase 1: per-pixel rotation params, 1 thread per px (32 px/block)
    if (tid < 32) {
        int r0 = tid >> 4, c0 = tid & 15;
        float den = 0.f, crn = 0.f, ccn = 0.f;
#pragma unroll
        for (int i = 0; i < 7; i++)
#pragma unroll
            for (int j = 0; j < 7; j++) {
                float v = Srow[r0 + i][c0 + j];
                den += v; crn += v*(float)i; ccn += v*(float)j;
            }
        float dt = den + EPSF;
        float cr = crn/dt - 3.0f;
        float cx = ccn/dt - 3.0f + EPSF;
        float r2 = cr*cr + cx*cx;
        float inv = r2 > 0.f ? rsqrtf(r2) : 0.f;
        float c_ = r2 > 0.f ? cx*inv : 1.0f;
        float s_ = cr*inv;
        const float scale = 1.0f + EPSF;
        float pc  = c_/scale, ps = s_/scale;
        float pxo = (6.0f - (c_*6.0f - s_*6.0f))*0.5f/scale;
        float pyo = (6.0f - (s_*6.0f + c_*6.0f))*0.5f/scale;
        pars[tid] = make_float4(pc, ps, pxo, pyo);
    }
    __syncthreads();
    // ---- xtb/pars read-only until the reduction barrier ----

    float4 pp = pars[(rh << 4) | m];       // params of this lane's pixel
    float pc = pp.x, ps = pp.y, pxo = pp.z, pyo = pp.w;

    const v8bf* wp = Wp + lane;            // + (nt*25+kb)*64
    const __bf16* patch = &xtb[rh][m][q*8];   // 7x7 window base, ch-slice q

    v4f acc0 = {0.f,0.f,0.f,0.f}, acc1 = {0.f,0.f,0.f,0.f};
    v4f acc2 = {0.f,0.f,0.f,0.f}, acc3 = {0.f,0.f,0.f,0.f};

    // K-quarter split: 7,6,6,6 steps
    int kb0 = (kh == 0) ? 0 : (7 + (kh - 1)*6);
    int nkb = (kh == 0) ? 7 : 6;
    int kblast = kb0 + nkb - 1;

    // proven round-3 body; W loads issued AFTER A-fragment build (short
    // wf live range keeps VGPR <= 64 for 8 waves/SIMD)
#pragma unroll 1
    for (int kb = kb0; kb <= kblast; kb++) {
        unsigned ukb = (unsigned)kb;
        int py = (int)(ukb/5u);
        int pxx = kb - py*5;
        float yy = (float)(py + 1);
        float xx = (float)(pxx + 1);

        float xin = pc*xx - ps*yy + pxo;
        float yin = ps*xx + pc*yy + pyo;
        float x0f = floorf(xin), y0f = floorf(yin);
        float wx1 = xin - x0f, wx0 = 1.0f - wx1;
        float wy1 = yin - y0f, wy0 = 1.0f - wy1;
        int ix0 = (int)x0f, iy0 = (int)y0f;
        int ix1 = ix0 + 1,  iy1 = iy0 + 1;

        v2f a8[4];
#pragma unroll
        for (int d = 0; d < 4; d++) a8[d] = (v2f){0.f, 0.f};

        auto corner = [&](int yi, int xi, float wgt) {
            bool valid = (xi >= 0) & (xi < 7) & (yi >= 0) & (yi < 7);
            int cy  = yi < 0 ? 0 : (yi > 6 ? 6 : yi);
            int cx2 = xi < 0 ? 0 : (xi > 6 ? 6 : xi);
            float wq = valid ? wgt : 0.0f;
            union { v8bf v; unsigned u[4]; } uv;
            uv.v = *(const v8bf*)(patch + (cy*22 + cx2)*XBS);
            v2f w2 = (v2f){wq, wq};
#pragma unroll
            for (int d = 0; d < 4; d++) {
                v2f val = (v2f){ __uint_as_float(uv.u[d] << 16),
                                 __uint_as_float(uv.u[d] & 0xffff0000u) };
                a8[d] += w2 * val;   // v_pk_fma_f32
            }
        };
        corner(iy0, ix0, wy0*wx0);
        corner(iy0, ix1, wy0*wx1);
        corner(iy1, ix0, wy1*wx0);
        corner(iy1, ix1, wy1*wx1);

        v8bf af;   // A-fragment: row=m(px col), k=kb*32+q*8..+8
#pragma unroll
        for (int d = 0; d < 4; d++) {
            af[2*d]   = (__bf16)a8[d].x;
            af[2*d+1] = (__bf16)a8[d].y;
        }

        v8bf wf0 = wp[(0*25 + kb)*64];
        v8bf wf1 = wp[(1*25 + kb)*64];
        v8bf wf2 = wp[(2*25 + kb)*64];
        v8bf wf3 = wp[(3*25 + kb)*64];

        acc0 = __builtin_amdgcn_mfma_f32_16x16x32_bf16(af, wf0, acc0, 0, 0, 0);
        acc1 = __builtin_amdgcn_mfma_f32_16x16x32_bf16(af, wf1, acc1, 0, 0, 0);
        acc2 = __builtin_amdgcn_mfma_f32_16x16x32_bf16(af, wf2, acc2, 0, 0, 0);
        acc3 = __builtin_amdgcn_mfma_f32_16x16x32_bf16(af, wf3, acc3, 0, 0, 0);
    }

    // split-K reduction: kh=1..3 publish, kh=0 waves sum + store
    if (kh != 0) {
        int p = kh - 1;
        *(v4f*)&redu[p][rh][lane][0]  = acc0;
        *(v4f*)&redu[p][rh][lane][4]  = acc1;
        *(v4f*)&redu[p][rh][lane][8]  = acc2;
        *(v4f*)&redu[p][rh][lane][12] = acc3;
    }
    __syncthreads();
    if (kh == 0) {
#pragma unroll
        for (int p = 0; p < 3; p++) {
            acc0 += *(const v4f*)&redu[p][rh][lane][0];
            acc1 += *(const v4f*)&redu[p][rh][lane][4];
            acc2 += *(const v4f*)&redu[p][rh][lane][8];
            acc3 += *(const v4f*)&redu[p][rh][lane][12];
        }

        float bv0 = bias[m], bv1 = bias[16 + m];
        float bv2 = bias[32 + m], bv3 = bias[48 + m];

        int ho = ho0 + rh;                 // always < 58
        size_t rowbase = (size_t)(b*HO + ho)*WO + wo0;
#pragma unroll
        for (int r = 0; r < 4; r++) {
            int px = q*4 + r;              // D row = (lane>>4)*4 + reg -> pixel col
            if (px < npx) {
                float* op = out + (rowbase + px)*NF + m;
                op[0]  = acc0[r] + bv0;
                op[16] = acc1[r] + bv1;
                op[32] = acc2[r] + bv2;
                op[48] = acc3[r] + bv3;
            }
        }
    }
}

extern "C" void kernel_launch(void* const* d_in, const int* in_sizes, int n_in,
                              void* d_out, int out_size, void* d_ws, size_t ws_size,
                              hipStream_t stream) {
    const float* x    = (const float*)d_in[0];
    const float* W    = (const float*)d_in[1];
    const float* bias = (const float*)d_in[2];
    float* out = (float*)d_out;
    __bf16* Wp = (__bf16*)d_ws;                    // 102,400 B

    k_wpack<<<dim3(200), 256, 0, stream>>>(W, Wp);
    k_main<<<dim3(4, 29, B_), 512, 0, stream>>>(x, (const v8bf*)Wp, bias, out);
}

// Round 7
// 75.385 us; speedup vs baseline: 1.4118x; 1.0152x over previous
//
#include <hip/hip_runtime.h>
#include <hip/hip_bf16.h>

#define EPSF 1e-7f
#define B_ 8
#define H_ 64
#define W_ 64
#define C_ 32
#define HO 58
#define WO 58
#define NF 64
#define KDIM 800

#define XBS 40      // xtb channel stride (bf16): 80B -> +20 banks/col, balanced 8/bank

typedef __bf16 v8bf __attribute__((ext_vector_type(8)));
typedef float  v4f  __attribute__((ext_vector_type(4)));
typedef float  v2f  __attribute__((ext_vector_type(2)));

// ---- pack W into MFMA B-fragment order, bf16 (proven) ----
// Wp[((nt*25+kb)*64+lane)*8+j] = W[f=nt*16+(lane&15)][k=kb*32+(lane>>4)*8+j]
__global__ void k_wpack(const float* __restrict__ W, __bf16* __restrict__ Wp) {
    int t = blockIdx.x*256 + threadIdx.x;   // 51200 total
    int j = t & 7; int lane = (t >> 3) & 63; int rest = t >> 9;
    int kb = rest % 25; int nt = rest / 25;
    int f = nt*16 + (lane & 15);
    int k = kb*32 + (lane >> 4)*8 + j;
    Wp[t] = (__bf16)W[f*KDIM + k];
}

// ---- fused: block = 4 rows x 16 cols (64 px), 8 waves = (row rh 0..3, K-half kh).
// All pieces individually proven: round-1 geometry/staging/pars, round-3
// ping-pong K-body + split-K reduction, round-5 512-thread launch.
__global__ __launch_bounds__(512, 4)
void k_main(const float* __restrict__ x, const v8bf* __restrict__ Wp,
            const float* __restrict__ bias, float* __restrict__ out) {
    __shared__ __bf16 xtb[10][22][XBS];   // 17,600 B
    __shared__ float  Srow[10][22];       //    880 B
    __shared__ float4 pars[64];           //  1,024 B
    __shared__ float  redu[4][64][20];    // 20,480 B -> 39,984 B total

    int tid = threadIdx.x;
    int wv = tid >> 6, lane = tid & 63;
    int m = lane & 15, q = lane >> 4;
    int rh = wv & 3, kh = wv >> 2;        // waves 0-3: kh=0; 4-7: kh=1

    // XCD-aware remap over 480 blocks (8 x 60, bijective)
    int L = blockIdx.x + 4*(blockIdx.y + 15*blockIdx.z);   // 0..479
    int newL = (L & 7)*60 + (L >> 3);
    int b   = newL / 60;
    int rem = newL - b*60;                 // 0..59
    int rg  = rem >> 2;                    // 0..14 -> row group of 4
    int cg  = rem & 3;                     // 0..3  -> col group of 16
    int ho0 = rg*4, wo0 = cg*16;
    int npx = WO - wo0; if (npx > 16) npx = 16;   // 16,16,16,10

    // phase 0: stage 10 rows x 22 cols x 32ch; clamp edges (dups feed only
    // masked pixels). Round-1-proven pattern.
    if (tid < 220) {
        int r = tid / 22, c = tid - r*22;
        int xr = ho0 + r; if (xr > H_-1) xr = H_-1;
        int xc = wo0 + c; if (xc > W_-1) xc = W_-1;
        const float* src = x + (size_t)((b*H_ + xr)*W_ + xc)*C_;
        float4 vq[8];
#pragma unroll
        for (int qq = 0; qq < 8; qq++) vq[qq] = *(const float4*)(src + qq*4);
        float s = 0.f;
#pragma unroll
        for (int qq = 0; qq < 8; qq++) s += vq[qq].x + vq[qq].y + vq[qq].z + vq[qq].w;
        Srow[r][c] = s;
#pragma unroll
        for (int h8 = 0; h8 < 4; h8++) {
            v8bf o;
            o[0]=(__bf16)vq[h8*2].x;   o[1]=(__bf16)vq[h8*2].y;
            o[2]=(__bf16)vq[h8*2].z;   o[3]=(__bf16)vq[h8*2].w;
            o[4]=(__bf16)vq[h8*2+1].x; o[5]=(__bf16)vq[h8*2+1].y;
            o[6]=(__bf16)vq[h8*2+1].z; o[7]=(__bf16)vq[h8*2+1].w;
            *(v8bf*)&xtb[r][c][h8*8] = o;
        }
    }
    __syncthreads();

    // phase 1: per-pixel rotation params, 1 thread per px (64 px/block)
    if (tid < 64) {
        int r0 = tid >> 4, c0 = tid & 15;
        float den = 0.f, crn = 0.f, ccn = 0.f;
#pragma unroll
        for (int i = 0; i < 7; i++)
#pragma unroll
            for (int j = 0; j < 7; j++) {
                float v = Srow[r0 + i][c0 + j];
                den += v; crn += v*(float)i; ccn += v*(float)j;
            }
        float dt = den + EPSF;
        float cr = crn/dt - 3.0f;
        float cx = ccn/dt - 3.0f + EPSF;
        float r2 = cr*cr + cx*cx;
        float inv = r2 > 0.f ? rsqrtf(r2) : 0.f;
        float c_ = r2 > 0.f ? cx*inv : 1.0f;
        float s_ = cr*inv;
        const float scale = 1.0f + EPSF;
        float pc  = c_/scale, ps = s_/scale;
        float pxo = (6.0f - (c_*6.0f - s_*6.0f))*0.5f/scale;
        float pyo = (6.0f - (s_*6.0f + c_*6.0f))*0.5f/scale;
        pars[tid] = make_float4(pc, ps, pxo, pyo);
    }
    __syncthreads();
    // ---- xtb/pars read-only until the reduction barrier ----

    float4 pp = pars[(rh << 4) | m];       // params of this lane's pixel
    float pc = pp.x, ps = pp.y, pxo = pp.z, pyo = pp.w;

    const v8bf* wp = Wp + lane;            // + (nt*25+kb)*64
    const __bf16* patch = &xtb[rh][m][q*8];   // 7x7 window base, ch-slice q

    v4f acc0 = {0.f,0.f,0.f,0.f}, acc1 = {0.f,0.f,0.f,0.f};
    v4f acc2 = {0.f,0.f,0.f,0.f}, acc3 = {0.f,0.f,0.f,0.f};

    int kb0 = kh*13;                       // kh=0: kb 0..12; kh=1: kb 13..24
    int nkb = 13 - kh;
    int kblast = kb0 + nkb - 1;

    auto loadw = [&](v8bf* dst, int kbi) {
        dst[0] = wp[(0*25 + kbi)*64];
        dst[1] = wp[(1*25 + kbi)*64];
        dst[2] = wp[(2*25 + kbi)*64];
        dst[3] = wp[(3*25 + kbi)*64];
    };

    auto body = [&](int kb, const v8bf* wf) {
        unsigned ukb = (unsigned)kb;
        int py = (int)(ukb/5u);
        int pxx = kb - py*5;
        float yy = (float)(py + 1);
        float xx = (float)(pxx + 1);

        float xin = pc*xx - ps*yy + pxo;
        float yin = ps*xx + pc*yy + pyo;
        float x0f = floorf(xin), y0f = floorf(yin);
        float wx1 = xin - x0f, wx0 = 1.0f - wx1;
        float wy1 = yin - y0f, wy0 = 1.0f - wy1;
        int ix0 = (int)x0f, iy0 = (int)y0f;
        int ix1 = ix0 + 1,  iy1 = iy0 + 1;

        v2f a8[4];
#pragma unroll
        for (int d = 0; d < 4; d++) a8[d] = (v2f){0.f, 0.f};

        auto corner = [&](int yi, int xi, float wgt) {
            bool valid = (xi >= 0) & (xi < 7) & (yi >= 0) & (yi < 7);
            int cy  = yi < 0 ? 0 : (yi > 6 ? 6 : yi);
            int cx2 = xi < 0 ? 0 : (xi > 6 ? 6 : xi);
            float wq = valid ? wgt : 0.0f;
            union { v8bf v; unsigned u[4]; } uv;
            uv.v = *(const v8bf*)(patch + (cy*22 + cx2)*XBS);
            v2f w2 = (v2f){wq, wq};
#pragma unroll
            for (int d = 0; d < 4; d++) {
                v2f val = (v2f){ __uint_as_float(uv.u[d] << 16),
                                 __uint_as_float(uv.u[d] & 0xffff0000u) };
                a8[d] += w2 * val;   // v_pk_fma_f32
            }
        };
        corner(iy0, ix0, wy0*wx0);
        corner(iy0, ix1, wy0*wx1);
        corner(iy1, ix0, wy1*wx0);
        corner(iy1, ix1, wy1*wx1);

        v8bf af;   // A-fragment: row=m(px col), k=kb*32+q*8..+8
#pragma unroll
        for (int d = 0; d < 4; d++) {
            af[2*d]   = (__bf16)a8[d].x;
            af[2*d+1] = (__bf16)a8[d].y;
        }
        acc0 = __builtin_amdgcn_mfma_f32_16x16x32_bf16(af, wf[0], acc0, 0, 0, 0);
        acc1 = __builtin_amdgcn_mfma_f32_16x16x32_bf16(af, wf[1], acc1, 0, 0, 0);
        acc2 = __builtin_amdgcn_mfma_f32_16x16x32_bf16(af, wf[2], acc2, 0, 0, 0);
        acc3 = __builtin_amdgcn_mfma_f32_16x16x32_bf16(af, wf[3], acc3, 0, 0, 0);
    };

    // round-3-proven ping-pong: W loads for step k+1 in flight during step k
    v8bf wfA[4], wfB[4];
    loadw(wfA, kb0);
    int i = 0;
#pragma unroll 1
    for (; i + 2 <= nkb; i += 2) {
        loadw(wfB, kb0 + i + 1);
        body(kb0 + i, wfA);
        int nx = kb0 + i + 2; if (nx > kblast) nx = kblast;
        loadw(wfA, nx);
        body(kb0 + i + 1, wfB);
    }
    if (i < nkb) body(kblast, wfA);        // tail (kh=0 only: 13th step)

    // split-K reduction: kh=1 waves publish, kh=0 waves sum + store
    if (kh == 1) {
        *(v4f*)&redu[rh][lane][0]  = acc0;
        *(v4f*)&redu[rh][lane][4]  = acc1;
        *(v4f*)&redu[rh][lane][8]  = acc2;
        *(v4f*)&redu[rh][lane][12] = acc3;
    }
    __syncthreads();
    if (kh == 0) {
        acc0 += *(const v4f*)&redu[rh][lane][0];
        acc1 += *(const v4f*)&redu[rh][lane][4];
        acc2 += *(const v4f*)&redu[rh][lane][8];
        acc3 += *(const v4f*)&redu[rh][lane][12];

        float bv0 = bias[m], bv1 = bias[16 + m];
        float bv2 = bias[32 + m], bv3 = bias[48 + m];

        int ho = ho0 + rh;
        if (ho < HO) {
            size_t rowbase = (size_t)(b*HO + ho)*WO + wo0;
#pragma unroll
            for (int r = 0; r < 4; r++) {
                int px = q*4 + r;          // D row = (lane>>4)*4 + reg -> pixel col
                if (px < npx) {
                    float* op = out + (rowbase + px)*NF + m;
                    op[0]  = acc0[r] + bv0;
                    op[16] = acc1[r] + bv1;
                    op[32] = acc2[r] + bv2;
                    op[48] = acc3[r] + bv3;
                }
            }
        }
    }
}

extern "C" void kernel_launch(void* const* d_in, const int* in_sizes, int n_in,
                              void* d_out, int out_size, void* d_ws, size_t ws_size,
                              hipStream_t stream) {
    const float* x    = (const float*)d_in[0];
    const float* W    = (const float*)d_in[1];
    const float* bias = (const float*)d_in[2];
    float* out = (float*)d_out;
    __bf16* Wp = (__bf16*)d_ws;                    // 102,400 B

    k_wpack<<<dim3(200), 256, 0, stream>>>(W, Wp);
    k_main<<<dim3(4, 15, B_), 512, 0, stream>>>(x, (const v8bf*)Wp, bias, out);
}